// Round 9
// baseline (412.458 us; speedup 1.0000x reference)
//
#include <hip/hip_runtime.h>

constexpr int B_ = 64, N_ = 32, I_ = 1152, D_ = 16, K_ = 8;
constexpr int SVD = B_ * N_ * D_;   // 32768

// Block: 256 thr = 4 waves; block = (ic chunk of ICLEN i's) x (bg: 16 batches).
// Wave w: batches bB..bB+3; lane -> (n = l&31, d-half = l>>5).
// W slice (16KB/i) double-buffered in LDS, ROTATION swizzle (granule (g+n)&31):
//   proven 0 bank conflicts (round 8). f32 end-to-end; softmax keeps max-sub
//   (round-7 NaN lesson: logits reach |l|>88).
// PACKED-PAIR softmax: one 32-lane butterfly serves TWO batches (half0=b_even,
//   half1=b_odd) -> 26 shfl/i/wave instead of 44.
// MODE 0: c = 1/32 (folded into reduce scale). MODE 1: c = softmax_n(uh . veff).
template <int MODE, int NIC>
__global__ __launch_bounds__(256, 4) void route9(
    const float* __restrict__ W, const float* __restrict__ x,
    const float* __restrict__ veff, float* __restrict__ partial)
{
    constexpr int ICLEN = I_ / NIC;
    __shared__ __align__(16) float wlds[2][4096];   // 2 x 16KB

    int bid = blockIdx.x;
    int ic, bg;
    if constexpr ((NIC & 7) == 0) {
        constexpr int icpx = NIC / 8;          // ic's per XCD (W slice stays L2-local)
        int x8 = bid & 7, r = bid >> 3;
        ic = x8 * icpx + (r % icpx);
        bg = r / icpx;
    } else { ic = bid >> 2; bg = bid & 3; }

    const int tid = threadIdx.x;
    const int w = tid >> 6, l = tid & 63;
    const int n = l & 31, d0 = (l >> 5) * 8;
    const int bB = bg * 16 + w * 4;
    const int i0 = ic * ICLEN;

    // W staging: thread stages row nsl, granules p0+8r (16B), rotation-swizzled
    const int nsl = tid >> 3, p0 = tid & 7;
    const float* wrow = W + (size_t)nsl * (I_ * D_ * K_) + (size_t)i0 * 128;

    float sacc[4][8];
#pragma unroll
    for (int bb = 0; bb < 4; ++bb)
#pragma unroll
        for (int j = 0; j < 8; ++j) sacc[bb][j] = 0.f;

    float4 st[4];
    auto stage_load = [&](int t) {
#pragma unroll
        for (int r = 0; r < 4; ++r)
            st[r] = *(const float4*)(wrow + (size_t)t * 128 + (p0 + 8 * r) * 4);
    };
    auto stage_write = [&](int buf) {
#pragma unroll
        for (int r = 0; r < 4; ++r) {
            int g = p0 + 8 * r;
            *(float4*)&wlds[buf][nsl * 128 + ((g + nsl) & 31) * 4] = st[r];
        }
    };

    stage_load(0);
    stage_write(0);

    for (int t = 0; t < ICLEN; ++t) {
        __syncthreads();                               // buf(t&1) staged & prev reads done
        if (t + 1 < ICLEN) stage_load(t + 1);          // VMEM overlaps compute
        const int buf = t & 1;
        const int i = i0 + t;

        float uh[4][8];
        if constexpr (MODE == 1) {
#pragma unroll
            for (int bb = 0; bb < 4; ++bb)
#pragma unroll
                for (int j = 0; j < 8; ++j) uh[bb][j] = 0.f;
        }

        // kh-split: xr holds 4 floats per batch at a time (16 VGPR, not 32)
#pragma unroll
        for (int kh = 0; kh < 2; ++kh) {
            float4 xv[4];
#pragma unroll
            for (int bb = 0; bb < 4; ++bb)
                xv[bb] = *(const float4*)(x + ((size_t)(bB + bb) * I_ + i) * K_ + kh * 4);
#pragma unroll
            for (int j = 0; j < 8; ++j) {
                int g = (d0 + j) * 2 + kh;
                float4 wv = *(const float4*)&wlds[buf][n * 128 + ((g + n) & 31) * 4];
#pragma unroll
                for (int bb = 0; bb < 4; ++bb) {
                    float acc = wv.x * xv[bb].x + wv.y * xv[bb].y +
                                wv.z * xv[bb].z + wv.w * xv[bb].w;
                    if constexpr (MODE == 0) sacc[bb][j] += acc;
                    else                     uh[bb][j] += acc;
                }
            }
        }

        if constexpr (MODE == 1) {
#pragma unroll
            for (int p = 0; p < 2; ++p) {
                const int b0i = 2 * p, b1i = 2 * p + 1;
                // ve re-read from L2 per pair (frees 32 VGPR vs register-resident)
                const float* vp0 = veff + ((size_t)(bB + b0i) * N_ + n) * D_ + d0;
                const float* vp1 = veff + ((size_t)(bB + b1i) * N_ + n) * D_ + d0;
                float4 va0 = *(const float4*)vp0, vb0 = *(const float4*)(vp0 + 4);
                float4 va1 = *(const float4*)vp1, vb1 = *(const float4*)(vp1 + 4);

                float bl0 = va0.x * uh[b0i][0] + va0.y * uh[b0i][1] +
                            va0.z * uh[b0i][2] + va0.w * uh[b0i][3] +
                            vb0.x * uh[b0i][4] + vb0.y * uh[b0i][5] +
                            vb0.z * uh[b0i][6] + vb0.w * uh[b0i][7];
                float bl1 = va1.x * uh[b1i][0] + va1.y * uh[b1i][1] +
                            va1.z * uh[b1i][2] + va1.w * uh[b1i][3] +
                            vb1.x * uh[b1i][4] + vb1.y * uh[b1i][5] +
                            vb1.z * uh[b1i][6] + vb1.w * uh[b1i][7];
                bl0 += __shfl_xor(bl0, 32);            // full-D dots
                bl1 += __shfl_xor(bl1, 32);
                // pack: half0 carries b0i's logit, half1 carries b1i's
                float lp = (l < 32) ? bl0 : bl1;
                float mx = lp;                         // max over n (overflow guard)
#pragma unroll
                for (int s2 = 16; s2 >= 1; s2 >>= 1) mx = fmaxf(mx, __shfl_xor(mx, s2));
                float e = __expf(lp - mx), sm = e;
#pragma unroll
                for (int s2 = 16; s2 >= 1; s2 >>= 1) sm += __shfl_xor(sm, s2);
                float cp = e / sm;
                float co = __shfl_xor(cp, 32);         // unpack: each half gets the other
                float c0 = (l < 32) ? cp : co;
                float c1 = (l < 32) ? co : cp;
#pragma unroll
                for (int j = 0; j < 8; ++j) {
                    sacc[b0i][j] = fmaf(c0, uh[b0i][j], sacc[b0i][j]);
                    sacc[b1i][j] = fmaf(c1, uh[b1i][j], sacc[b1i][j]);
                }
            }
        }

        if (t + 1 < ICLEN) stage_write((t + 1) & 1);
    }

    // flush partial: partial[ic][b][n][d], float4x2 per lane per bb
#pragma unroll
    for (int bb = 0; bb < 4; ++bb) {
        float* pb = partial + (size_t)ic * 32768 + (bB + bb) * 512 + n * 16 + d0;
        *(float4*)pb       = make_float4(sacc[bb][0], sacc[bb][1], sacc[bb][2], sacc[bb][3]);
        *(float4*)(pb + 4) = make_float4(sacc[bb][4], sacc[bb][5], sacc[bb][6], sacc[bb][7]);
    }
}

// Reduce NIC partials + squash, one thread per output element (coalesced).
// RM 0: vout=squash  1: vout=vprev+squash  2: out=sigmoid(squash*dw+db)
template <int RM, int NIC>
__global__ __launch_bounds__(256) void reduce9(
    const float* __restrict__ partial, float scale,
    const float* __restrict__ vprev, float* __restrict__ vout,
    const float* __restrict__ dw, const float* __restrict__ db,
    float* __restrict__ out)
{
    int e = blockIdx.x * 256 + threadIdx.x;           // grid 128 -> 32768 elems
    float a0 = 0.f, a1 = 0.f, a2 = 0.f, a3 = 0.f;
    const float* p = partial + e;
#pragma unroll 2
    for (int q = 0; q + 4 <= NIC; q += 4) {
        a0 += p[(size_t)(q + 0) * 32768];
        a1 += p[(size_t)(q + 1) * 32768];
        a2 += p[(size_t)(q + 2) * 32768];
        a3 += p[(size_t)(q + 3) * 32768];
    }
    if constexpr (NIC & 3) {
        for (int q = NIC & ~3; q < NIC; ++q) a0 += p[(size_t)q * 32768];
    }
    float ss = ((a0 + a1) + (a2 + a3)) * scale;

    float sq = ss * ss;
    float sc = sq / (1.f + sq) / sqrtf(sq + 1e-7f);
    float v = sc * ss;
    if constexpr (RM == 0) {
        vout[e] = v;
    } else if constexpr (RM == 1) {
        vout[e] = vprev[e] + v;
    } else {
        float z = v * dw[0] + db[0];
        out[e] = 1.f / (1.f + __expf(-z));
    }
}

template <int NIC>
static void run_pipeline(const float* W, const float* x, const float* dw,
                         const float* db, float* out, void* d_ws, hipStream_t stream)
{
    float* partial = (float*)d_ws;
    float* vA = partial + (size_t)NIC * 32768;
    float* vB = vA + SVD;
    dim3 rblk(256), rgrid(NIC * 4), dgrid(SVD / 256);

    route9<0, NIC><<<rgrid, rblk, 0, stream>>>(W, x, nullptr, partial);
    reduce9<0, NIC><<<dgrid, rblk, 0, stream>>>(partial, 1.f / 32.f, nullptr, vA, nullptr, nullptr, nullptr);
    route9<1, NIC><<<rgrid, rblk, 0, stream>>>(W, x, vA, partial);
    reduce9<1, NIC><<<dgrid, rblk, 0, stream>>>(partial, 1.f, vA, vB, nullptr, nullptr, nullptr);
    route9<1, NIC><<<rgrid, rblk, 0, stream>>>(W, x, vB, partial);
    reduce9<2, NIC><<<dgrid, rblk, 0, stream>>>(partial, 1.f, nullptr, nullptr, dw, db, out);
}

extern "C" void kernel_launch(void* const* d_in, const int* in_sizes, int n_in,
                              void* d_out, int out_size, void* d_ws, size_t ws_size,
                              hipStream_t stream)
{
    const float* x  = (const float*)d_in[0];
    const float* W  = (const float*)d_in[1];
    const float* dw = (const float*)d_in[2];
    const float* db = (const float*)d_in[3];
    float* out = (float*)d_out;

    // f32 partials: NIC=288 needs 288*128KB = 36.9MB (+256KB v).
    const size_t needMain = (size_t)288 * 32768 * 4 + 2ull * SVD * 4;
    if (ws_size >= needMain)
        run_pipeline<288>(W, x, dw, db, out, d_ws, stream);   // grid 1152 = 4.5 blk/CU
    else
        run_pipeline<36>(W, x, dw, db, out, d_ws, stream);    // ~4.9MB fallback
}

// Round 10
// 193.152 us; speedup vs baseline: 2.1354x; 2.1354x over previous
//
#include <hip/hip_runtime.h>

constexpr int B_ = 64, N_ = 32, I_ = 1152, D_ = 16, K_ = 8;
constexpr int SVD = B_ * N_ * D_;   // 32768

// ---------------------------------------------------------------------------
// W transpose: W[n,i,d,k] -> Wt[i][p][l][c]  (one-time, amortized over 3 routes)
//   lane l = n + 32*(d>>3), piece p = (d&7)*2 + (k>>2), c = k&3
// Route lane l then reads its 16 pieces at Wt + i*4096 + p*256 + l*4:
//   per piece a wave reads 64*16B = 1KB CONTIGUOUS -> no LDS staging needed.
// ---------------------------------------------------------------------------
__global__ __launch_bounds__(256) void wtrans(const float* __restrict__ W,
                                              float* __restrict__ Wt)
{
    int i = blockIdx.x;                 // 1152 blocks
    int tid = threadIdx.x;
    int n = tid >> 3, q = tid & 7;      // thread reads W[n][i][2q..2q+1][0..7]
    const float* src = W + (size_t)n * (I_ * D_ * K_) + (size_t)i * 128 + q * 16;
    float* dst = Wt + (size_t)i * 4096;
#pragma unroll
    for (int f = 0; f < 4; ++f) {
        float4 v = *(const float4*)(src + f * 4);
        int d = 2 * q + (f >> 1);
        int p = (d & 7) * 2 + (f & 1);
        int l = n + 32 * (d >> 3);
        *(float4*)(dst + p * 256 + l * 4) = v;
    }
}

// ---------------------------------------------------------------------------
// Barrier-free route: no LDS, no __syncthreads. Block: 256 thr = 4 waves,
// block = (ic chunk of ICLEN i's) x (bg: 16 batches); wave w: batches bB..bB+3;
// lane -> (n = l&31, d-half = l>>5). f32 end-to-end. Softmax keeps max-sub
// (round-7 NaN: logits exceed 88). PACKED-PAIR softmax (round-9, correctness
// proven): one 32-lane butterfly serves two batches. (256,2): VGPR >= 128
// required -- (256,3)/(256,4) spill catastrophically (rounds 6,9).
// MODE 0: c = 1/32 (folded into reduce scale). MODE 1: c = softmax_n(uh . veff).
// ---------------------------------------------------------------------------
template <int MODE, int NIC>
__global__ __launch_bounds__(256, 2) void routeT(
    const float* __restrict__ Wt, const float* __restrict__ x,
    const float* __restrict__ veff, float* __restrict__ partial)
{
    constexpr int ICLEN = I_ / NIC;
    int bid = blockIdx.x;
    int ic, bg;
    if constexpr ((NIC & 7) == 0) {
        constexpr int icpx = NIC / 8;          // ic's per XCD: Wt chunk L2-resident
        int x8 = bid & 7, r = bid >> 3;
        ic = x8 * icpx + (r % icpx);
        bg = r / icpx;
    } else { ic = bid >> 2; bg = bid & 3; }

    const int tid = threadIdx.x;
    const int w = tid >> 6, l = tid & 63;
    const int n = l & 31, d0 = (l >> 5) * 8;
    const int bB = bg * 16 + w * 4;
    const int i0 = ic * ICLEN;

    float ve[4][8];
    if constexpr (MODE == 1) {
#pragma unroll
        for (int bb = 0; bb < 4; ++bb) {
            const float* vp = veff + ((size_t)(bB + bb) * N_ + n) * D_ + d0;
            float4 a = *(const float4*)vp, b = *(const float4*)(vp + 4);
            ve[bb][0] = a.x;  ve[bb][1] = a.y;  ve[bb][2] = a.z;  ve[bb][3] = a.w;
            ve[bb][4] = b.x;  ve[bb][5] = b.y;  ve[bb][6] = b.z;  ve[bb][7] = b.w;
        }
    }

    float sacc[4][8];
#pragma unroll
    for (int bb = 0; bb < 4; ++bb)
#pragma unroll
        for (int j = 0; j < 8; ++j) sacc[bb][j] = 0.f;

    const float* wl = Wt + (size_t)i0 * 4096 + l * 4;   // per-lane W base

    for (int t = 0; t < ICLEN; ++t) {
        const int i = i0 + t;
        const float* wi = wl + (size_t)t * 4096;

        // x[b,i,:]: wave-uniform broadcast loads (one line each, L2-hot)
        float4 xv[4][2];
#pragma unroll
        for (int bb = 0; bb < 4; ++bb) {
            const float* xp = x + ((size_t)(bB + bb) * I_ + i) * K_;
            xv[bb][0] = *(const float4*)xp;
            xv[bb][1] = *(const float4*)(xp + 4);
        }

        float uh[4][8];
#pragma unroll
        for (int j = 0; j < 8; ++j) {
            float4 w0 = *(const float4*)(wi + (j * 2    ) * 256);   // kh=0
            float4 w1 = *(const float4*)(wi + (j * 2 + 1) * 256);   // kh=1
#pragma unroll
            for (int bb = 0; bb < 4; ++bb) {
                float acc = w0.x * xv[bb][0].x + w0.y * xv[bb][0].y +
                            w0.z * xv[bb][0].z + w0.w * xv[bb][0].w +
                            w1.x * xv[bb][1].x + w1.y * xv[bb][1].y +
                            w1.z * xv[bb][1].z + w1.w * xv[bb][1].w;
                if constexpr (MODE == 0) sacc[bb][j] += acc;
                else                     uh[bb][j] = acc;
            }
        }

        if constexpr (MODE == 1) {
#pragma unroll
            for (int p2 = 0; p2 < 2; ++p2) {
                const int b0i = 2 * p2, b1i = 2 * p2 + 1;
                float bl0 = 0.f, bl1 = 0.f;
#pragma unroll
                for (int j = 0; j < 8; ++j) {
                    bl0 += uh[b0i][j] * ve[b0i][j];
                    bl1 += uh[b1i][j] * ve[b1i][j];
                }
                bl0 += __shfl_xor(bl0, 32);            // full-D dots
                bl1 += __shfl_xor(bl1, 32);
                // pack: half0 carries b0i's logit, half1 carries b1i's
                float lp = (l < 32) ? bl0 : bl1;
                float mx = lp;                         // max over n (overflow guard)
#pragma unroll
                for (int s2 = 16; s2 >= 1; s2 >>= 1) mx = fmaxf(mx, __shfl_xor(mx, s2));
                float e = __expf(lp - mx), sm = e;
#pragma unroll
                for (int s2 = 16; s2 >= 1; s2 >>= 1) sm += __shfl_xor(sm, s2);
                float cp = e / sm;
                float co = __shfl_xor(cp, 32);         // swap halves
                float c0 = (l < 32) ? cp : co;
                float c1 = (l < 32) ? co : cp;
#pragma unroll
                for (int j = 0; j < 8; ++j) {
                    sacc[b0i][j] = fmaf(c0, uh[b0i][j], sacc[b0i][j]);
                    sacc[b1i][j] = fmaf(c1, uh[b1i][j], sacc[b1i][j]);
                }
            }
        }
    }

    // flush partial: partial[ic][b][n][d], float4x2 per lane per bb
#pragma unroll
    for (int bb = 0; bb < 4; ++bb) {
        float* pb = partial + (size_t)ic * 32768 + (bB + bb) * 512 + n * 16 + d0;
        *(float4*)pb       = make_float4(sacc[bb][0], sacc[bb][1], sacc[bb][2], sacc[bb][3]);
        *(float4*)(pb + 4) = make_float4(sacc[bb][4], sacc[bb][5], sacc[bb][6], sacc[bb][7]);
    }
}

// Reduce NIC partials + squash, one thread per output element (coalesced).
// RM 0: vout=squash  1: vout=vprev+squash  2: out=sigmoid(squash*dw+db)
template <int RM, int NIC>
__global__ __launch_bounds__(256) void reduceT(
    const float* __restrict__ partial, float scale,
    const float* __restrict__ vprev, float* __restrict__ vout,
    const float* __restrict__ dw, const float* __restrict__ db,
    float* __restrict__ out)
{
    int e = blockIdx.x * 256 + threadIdx.x;           // grid 128 -> 32768 elems
    float a0 = 0.f, a1 = 0.f, a2 = 0.f, a3 = 0.f;
    const float* p = partial + e;
#pragma unroll 2
    for (int q = 0; q + 4 <= NIC; q += 4) {
        a0 += p[(size_t)(q + 0) * 32768];
        a1 += p[(size_t)(q + 1) * 32768];
        a2 += p[(size_t)(q + 2) * 32768];
        a3 += p[(size_t)(q + 3) * 32768];
    }
    if constexpr (NIC & 3) {
        for (int q = NIC & ~3; q < NIC; ++q) a0 += p[(size_t)q * 32768];
    }
    float ss = ((a0 + a1) + (a2 + a3)) * scale;

    float sq = ss * ss;
    float sc = sq / (1.f + sq) / sqrtf(sq + 1e-7f);
    float v = sc * ss;
    if constexpr (RM == 0) {
        vout[e] = v;
    } else if constexpr (RM == 1) {
        vout[e] = vprev[e] + v;
    } else {
        float z = v * dw[0] + db[0];
        out[e] = 1.f / (1.f + __expf(-z));
    }
}

template <int NIC>
static void run_pipeline(const float* W, const float* x, const float* dw,
                         const float* db, float* out, void* d_ws, hipStream_t stream)
{
    float* Wt = (float*)d_ws;                          // 1152*4096 f = 18.9MB
    float* partial = Wt + (size_t)I_ * 4096;
    float* vA = partial + (size_t)NIC * 32768;
    float* vB = vA + SVD;
    dim3 rblk(256), rgrid(NIC * 4), dgrid(SVD / 256);

    wtrans<<<I_, 256, 0, stream>>>(W, Wt);
    routeT<0, NIC><<<rgrid, rblk, 0, stream>>>(Wt, x, nullptr, partial);
    reduceT<0, NIC><<<dgrid, rblk, 0, stream>>>(partial, 1.f / 32.f, nullptr, vA, nullptr, nullptr, nullptr);
    routeT<1, NIC><<<rgrid, rblk, 0, stream>>>(Wt, x, vA, partial);
    reduceT<1, NIC><<<dgrid, rblk, 0, stream>>>(partial, 1.f, vA, vB, nullptr, nullptr, nullptr);
    routeT<1, NIC><<<rgrid, rblk, 0, stream>>>(Wt, x, vB, partial);
    reduceT<2, NIC><<<dgrid, rblk, 0, stream>>>(partial, 1.f, nullptr, nullptr, dw, db, out);
}

extern "C" void kernel_launch(void* const* d_in, const int* in_sizes, int n_in,
                              void* d_out, int out_size, void* d_ws, size_t ws_size,
                              hipStream_t stream)
{
    const float* x  = (const float*)d_in[0];
    const float* W  = (const float*)d_in[1];
    const float* dw = (const float*)d_in[2];
    const float* db = (const float*)d_in[3];
    float* out = (float*)d_out;

    const size_t wtB = (size_t)I_ * 4096 * 4;                       // 18.9MB
    const size_t need192 = wtB + (size_t)192 * 32768 * 4 + 2ull * SVD * 4;  // ~44MB
    const size_t need36  = wtB + (size_t)36  * 32768 * 4 + 2ull * SVD * 4;  // ~24MB
    if (ws_size >= need192)
        run_pipeline<192>(W, x, dw, db, out, d_ws, stream);   // grid 768 = 3 blk/CU
    else if (ws_size >= need36)
        run_pipeline<36>(W, x, dw, db, out, d_ws, stream);
    else
        run_pipeline<4>(W, x, dw, db, out, d_ws, stream);     // minimal scratch
}

// Round 11
// 157.069 us; speedup vs baseline: 2.6260x; 1.2297x over previous
//
#include <hip/hip_runtime.h>

constexpr int B_ = 64, N_ = 32, I_ = 1152, D_ = 16, K_ = 8;
constexpr int SVD = B_ * N_ * D_;   // 32768

// ---------------------------------------------------------------------------
// W transpose: W[n,i,d,k] -> Wt[i][p][l][c]  (one-time, amortized over 3 routes)
//   lane l = n + 32*(d>>3), piece p = (d&7)*2 + (k>>2), c = k&3
// Route lane l reads its 16 pieces at Wt + i*4096 + p*256 + l*4:
//   per piece a wave reads 64*16B = 1KB CONTIGUOUS -> no LDS staging needed.
// ---------------------------------------------------------------------------
__global__ __launch_bounds__(256) void wtrans(const float* __restrict__ W,
                                              float* __restrict__ Wt)
{
    int i = blockIdx.x;                 // 1152 blocks
    int tid = threadIdx.x;
    int n = tid >> 3, q = tid & 7;      // thread reads W[n][i][2q..2q+1][0..7]
    const float* src = W + (size_t)n * (I_ * D_ * K_) + (size_t)i * 128 + q * 16;
    float* dst = Wt + (size_t)i * 4096;
#pragma unroll
    for (int f = 0; f < 4; ++f) {
        float4 v = *(const float4*)(src + f * 4);
        int d = 2 * q + (f >> 1);
        int p = (d & 7) * 2 + (f & 1);
        int l = n + 32 * (d >> 3);
        *(float4*)(dst + p * 256 + l * 4) = v;
    }
}

// ---------------------------------------------------------------------------
// Barrier-free route, 2 batches/wave (short chain, many waves).
// Block: 256 thr = 4 waves; block = (ic chunk of ICLEN i's) x (bg: 8 batches).
// Wave w: batches bB=bg*8+w*2, bB+1; lane -> (n = l&31, d-half = l>>5).
// Grid = NIC*8 = 1536 -> 6 blk/CU launched; VGPR ~100 -> ~16-20 waves/CU res.
// f32 end-to-end; softmax keeps max-sub (round-7 NaN: logits exceed 88).
// Packed-pair softmax: half0 carries batch bB's logit, half1 carries bB+1's ->
// one 32-lane butterfly serves both batches. (256,2): VGPR>=128 required,
// (256,3)/(256,4) spill catastrophically (rounds 6,9).
// MODE 0: c = 1/32 (folded into reduce scale). MODE 1: c = softmax_n(uh . veff).
// ---------------------------------------------------------------------------
template <int MODE, int NIC>
__global__ __launch_bounds__(256, 2) void routeU(
    const float* __restrict__ Wt, const float* __restrict__ x,
    const float* __restrict__ veff, float* __restrict__ partial)
{
    constexpr int ICLEN = I_ / NIC;
    int bid = blockIdx.x;
    int ic, bg;
    if constexpr ((NIC & 7) == 0) {
        constexpr int icpx = NIC / 8;          // ic's per XCD: Wt chunk L2-resident
        int x8 = bid & 7, r = bid >> 3;
        ic = x8 * icpx + (r % icpx);
        bg = r / icpx;
    } else { ic = bid >> 3; bg = bid & 7; }

    const int tid = threadIdx.x;
    const int w = tid >> 6, l = tid & 63;
    const int n = l & 31, d0 = (l >> 5) * 8;
    const int bB = bg * 8 + w * 2;
    const int i0 = ic * ICLEN;

    float ve[2][8];
    if constexpr (MODE == 1) {
#pragma unroll
        for (int bb = 0; bb < 2; ++bb) {
            const float* vp = veff + ((size_t)(bB + bb) * N_ + n) * D_ + d0;
            float4 a = *(const float4*)vp, b = *(const float4*)(vp + 4);
            ve[bb][0] = a.x;  ve[bb][1] = a.y;  ve[bb][2] = a.z;  ve[bb][3] = a.w;
            ve[bb][4] = b.x;  ve[bb][5] = b.y;  ve[bb][6] = b.z;  ve[bb][7] = b.w;
        }
    }

    float sacc[2][8];
#pragma unroll
    for (int bb = 0; bb < 2; ++bb)
#pragma unroll
        for (int j = 0; j < 8; ++j) sacc[bb][j] = 0.f;

    const float* wl = Wt + (size_t)i0 * 4096 + l * 4;   // per-lane W base

    // x prefetch: next step's loads issue before current step's compute
    float4 xn[2][2];
#pragma unroll
    for (int bb = 0; bb < 2; ++bb) {
        const float* xp = x + ((size_t)(bB + bb) * I_ + i0) * K_;
        xn[bb][0] = *(const float4*)xp;
        xn[bb][1] = *(const float4*)(xp + 4);
    }

    for (int t = 0; t < ICLEN; ++t) {
        float4 xv[2][2];
#pragma unroll
        for (int bb = 0; bb < 2; ++bb) { xv[bb][0] = xn[bb][0]; xv[bb][1] = xn[bb][1]; }
        if (t + 1 < ICLEN) {
#pragma unroll
            for (int bb = 0; bb < 2; ++bb) {
                const float* xp = x + ((size_t)(bB + bb) * I_ + (i0 + t + 1)) * K_;
                xn[bb][0] = *(const float4*)xp;
                xn[bb][1] = *(const float4*)(xp + 4);
            }
        }

        const float* wi = wl + (size_t)t * 4096;
        float uh[2][8];
#pragma unroll
        for (int j = 0; j < 8; ++j) {
            float4 w0 = *(const float4*)(wi + (j * 2    ) * 256);   // kh=0
            float4 w1 = *(const float4*)(wi + (j * 2 + 1) * 256);   // kh=1
#pragma unroll
            for (int bb = 0; bb < 2; ++bb) {
                float acc = w0.x * xv[bb][0].x + w0.y * xv[bb][0].y +
                            w0.z * xv[bb][0].z + w0.w * xv[bb][0].w +
                            w1.x * xv[bb][1].x + w1.y * xv[bb][1].y +
                            w1.z * xv[bb][1].z + w1.w * xv[bb][1].w;
                if constexpr (MODE == 0) sacc[bb][j] += acc;
                else                     uh[bb][j] = acc;
            }
        }

        if constexpr (MODE == 1) {
            float bl0 = 0.f, bl1 = 0.f;
#pragma unroll
            for (int j = 0; j < 8; ++j) {
                bl0 += uh[0][j] * ve[0][j];
                bl1 += uh[1][j] * ve[1][j];
            }
            bl0 += __shfl_xor(bl0, 32);            // full-D dots
            bl1 += __shfl_xor(bl1, 32);
            // pack: half0 carries batch bB's logit, half1 carries bB+1's
            float lp = (l < 32) ? bl0 : bl1;
            float mx = lp;                         // max over n (overflow guard)
#pragma unroll
            for (int s2 = 16; s2 >= 1; s2 >>= 1) mx = fmaxf(mx, __shfl_xor(mx, s2));
            float e = __expf(lp - mx), sm = e;
#pragma unroll
            for (int s2 = 16; s2 >= 1; s2 >>= 1) sm += __shfl_xor(sm, s2);
            float cp = e / sm;
            float co = __shfl_xor(cp, 32);         // swap halves
            float c0 = (l < 32) ? cp : co;
            float c1 = (l < 32) ? co : cp;
#pragma unroll
            for (int j = 0; j < 8; ++j) {
                sacc[0][j] = fmaf(c0, uh[0][j], sacc[0][j]);
                sacc[1][j] = fmaf(c1, uh[1][j], sacc[1][j]);
            }
        }
    }

    // flush partial: partial[ic][b][n][d], float4x2 per lane per bb
#pragma unroll
    for (int bb = 0; bb < 2; ++bb) {
        float* pb = partial + (size_t)ic * 32768 + (bB + bb) * 512 + n * 16 + d0;
        *(float4*)pb       = make_float4(sacc[bb][0], sacc[bb][1], sacc[bb][2], sacc[bb][3]);
        *(float4*)(pb + 4) = make_float4(sacc[bb][4], sacc[bb][5], sacc[bb][6], sacc[bb][7]);
    }
}

// Reduce NIC partials + squash, one thread per output element (coalesced).
// RM 0: vout=squash  1: vout=vprev+squash  2: out=sigmoid(squash*dw+db)
template <int RM, int NIC>
__global__ __launch_bounds__(256) void reduceU(
    const float* __restrict__ partial, float scale,
    const float* __restrict__ vprev, float* __restrict__ vout,
    const float* __restrict__ dw, const float* __restrict__ db,
    float* __restrict__ out)
{
    int e = blockIdx.x * 256 + threadIdx.x;           // grid 128 -> 32768 elems
    float a0 = 0.f, a1 = 0.f, a2 = 0.f, a3 = 0.f;
    const float* p = partial + e;
#pragma unroll 2
    for (int q = 0; q + 4 <= NIC; q += 4) {
        a0 += p[(size_t)(q + 0) * 32768];
        a1 += p[(size_t)(q + 1) * 32768];
        a2 += p[(size_t)(q + 2) * 32768];
        a3 += p[(size_t)(q + 3) * 32768];
    }
    if constexpr (NIC & 3) {
        for (int q = NIC & ~3; q < NIC; ++q) a0 += p[(size_t)q * 32768];
    }
    float ss = ((a0 + a1) + (a2 + a3)) * scale;

    float sq = ss * ss;
    float sc = sq / (1.f + sq) / sqrtf(sq + 1e-7f);
    float v = sc * ss;
    if constexpr (RM == 0) {
        vout[e] = v;
    } else if constexpr (RM == 1) {
        vout[e] = vprev[e] + v;
    } else {
        float z = v * dw[0] + db[0];
        out[e] = 1.f / (1.f + __expf(-z));
    }
}

template <int NIC>
static void run_pipeline(const float* W, const float* x, const float* dw,
                         const float* db, float* out, void* d_ws, hipStream_t stream)
{
    float* Wt = (float*)d_ws;                          // 1152*4096 f = 18.9MB
    float* partial = Wt + (size_t)I_ * 4096;
    float* vA = partial + (size_t)NIC * 32768;
    float* vB = vA + SVD;
    dim3 rblk(256), rgrid(NIC * 8), dgrid(SVD / 256);

    wtrans<<<I_, 256, 0, stream>>>(W, Wt);
    routeU<0, NIC><<<rgrid, rblk, 0, stream>>>(Wt, x, nullptr, partial);
    reduceU<0, NIC><<<dgrid, rblk, 0, stream>>>(partial, 1.f / 32.f, nullptr, vA, nullptr, nullptr, nullptr);
    routeU<1, NIC><<<rgrid, rblk, 0, stream>>>(Wt, x, vA, partial);
    reduceU<1, NIC><<<dgrid, rblk, 0, stream>>>(partial, 1.f, vA, vB, nullptr, nullptr, nullptr);
    routeU<1, NIC><<<rgrid, rblk, 0, stream>>>(Wt, x, vB, partial);
    reduceU<2, NIC><<<dgrid, rblk, 0, stream>>>(partial, 1.f, nullptr, nullptr, dw, db, out);
}

extern "C" void kernel_launch(void* const* d_in, const int* in_sizes, int n_in,
                              void* d_out, int out_size, void* d_ws, size_t ws_size,
                              hipStream_t stream)
{
    const float* x  = (const float*)d_in[0];
    const float* W  = (const float*)d_in[1];
    const float* dw = (const float*)d_in[2];
    const float* db = (const float*)d_in[3];
    float* out = (float*)d_out;

    const size_t wtB = (size_t)I_ * 4096 * 4;                       // 18.9MB
    const size_t need192 = wtB + (size_t)192 * 32768 * 4 + 2ull * SVD * 4;  // ~43.4MB
    const size_t need36  = wtB + (size_t)36  * 32768 * 4 + 2ull * SVD * 4;  // ~24MB
    if (ws_size >= need192)
        run_pipeline<192>(W, x, dw, db, out, d_ws, stream);   // grid 1536 = 6 blk/CU
    else if (ws_size >= need36)
        run_pipeline<36>(W, x, dw, db, out, d_ws, stream);
    else
        run_pipeline<4>(W, x, dw, db, out, d_ws, stream);     // minimal scratch
}